// Round 3
// baseline (110.199 us; speedup 1.0000x reference)
//
#include <hip/hip_runtime.h>
#include <math.h>

// Problem constants
#define BATCH 1024
#define FEAT  512
#define NT    64
#define DDIM  1024          // CSETSIZE(64) * Nrf(4) * Nrf(4)

typedef __attribute__((ext_vector_type(8))) short  short8;
typedef __attribute__((ext_vector_type(4))) float  floatx4;

// fp32 -> bf16 round-to-nearest-even
__device__ __forceinline__ unsigned short bf16rne(float f) {
    unsigned int u = __float_as_uint(f);
    return (unsigned short)((u + 0x7fffu + ((u >> 16) & 1u)) >> 16);
}

__device__ __forceinline__ short8 cvt8(float4 a, float4 b) {
    short8 o;
    o[0] = (short)bf16rne(a.x); o[1] = (short)bf16rne(a.y);
    o[2] = (short)bf16rne(a.z); o[3] = (short)bf16rne(a.w);
    o[4] = (short)bf16rne(b.x); o[5] = (short)bf16rne(b.y);
    o[6] = (short)bf16rne(b.z); o[7] = (short)bf16rne(b.w);
    return o;
}

// ===========================================================================
// Single launch. No workspace, no pre-conversion pass.
//   blocks [0,512):     MFMA D-GEMM, 64x64 tiles. rt=bid&15, ct=bid>>4.
//                       Staging = fp32 global loads -> in-register bf16
//                       convert -> swizzled ds_write, double-buffered,
//                       1 barrier per k-step. Inputs are L2-resident
//                       (x 2MB, W_Dr/W_Di 4MB), so redundant per-block
//                       conversion is cheap; GEMM rides in the shadow of
//                       the fill's 34 MB of HBM writes.
//   blocks [512,4608):  A_real/A_imag diagonal fill; theta computed inline
//                       as fp32 dot products (hidden under streaming writes).
//   blocks [4608,4624): CSet pass-through.
// LDS tile format (8 KB = 64 rows x 128 B), 16B chunks XOR-swizzled:
// chunk c of row r stored at chunk position c^(r&7). B-tile row n holds
// (h?W_Di:W_Dr) col ct*32+g*16+pos, g=n>>5, h=(n>>4)&1, pos=n&15.
// ===========================================================================
__global__ __launch_bounds__(256) void k_mega(
    const float* __restrict__ x,
    const float* __restrict__ W_A,
    const float* __restrict__ b_A,
    const float* __restrict__ W_Dr,
    const float* __restrict__ b_Dr,
    const float* __restrict__ W_Di,
    const float* __restrict__ b_Di,
    const float* __restrict__ cset,
    float* __restrict__ out)
{
    __shared__ __align__(16) unsigned char smem[32768];   // 2 bufs x (8KB A + 8KB B)

    const int beta = blockIdx.x;
    const int tid  = threadIdx.x;

    if (beta < 512) {
        // ---- MFMA D-GEMM with fused fp32->bf16 staging ----
        const int rt   = beta & 15;
        const int ct   = beta >> 4;        // 0..31
        const int lane = tid & 63;
        const int wv   = tid >> 6;
        const int ln   = lane & 15;
        const int quad = lane >> 4;
        const int row0 = rt * 64;

        // staging mapping: thread -> (row r, even chunk-pair cp)
        const int r  = tid >> 2;           // 0..63
        const int cp = (tid & 3) * 2;      // 0,2,4,6
        const int s  = r & 7;
        const int d0 = r * 128 + ((cp ^ s) * 16);
        const int d1 = r * 128 + (((cp + 1) ^ s) * 16);
        const float* srcA = x + (size_t)(row0 + r) * FEAT + cp * 8;
        const int g = r >> 5, h = (r >> 4) & 1, pos = r & 15;
        const float* srcB =
            (h ? W_Di : W_Dr) + (size_t)(ct * 32 + g * 16 + pos) * FEAT + cp * 8;

        // prefetch kb=0 into registers
        float4 ra0 = *(const float4*)(srcA + 0);
        float4 ra1 = *(const float4*)(srcA + 4);
        float4 ra2 = *(const float4*)(srcA + 8);
        float4 ra3 = *(const float4*)(srcA + 12);
        float4 rb0 = *(const float4*)(srcB + 0);
        float4 rb1 = *(const float4*)(srcB + 4);
        float4 rb2 = *(const float4*)(srcB + 8);
        float4 rb3 = *(const float4*)(srcB + 12);

        floatx4 acc[4] = {{0,0,0,0},{0,0,0,0},{0,0,0,0},{0,0,0,0}};
        const int rowOffA = (wv * 16 + ln) * 128;
        const int swz = ln & 7;
        int cur = 0;

        #pragma unroll 1
        for (int kb = 0; kb < 8; ++kb) {
            unsigned char* La = smem + cur * 16384;
            unsigned char* Lb = La + 8192;
            // convert + swizzled store of the prefetched k-step
            *(short8*)(La + d0) = cvt8(ra0, ra1);
            *(short8*)(La + d1) = cvt8(ra2, ra3);
            *(short8*)(Lb + d0) = cvt8(rb0, rb1);
            *(short8*)(Lb + d1) = cvt8(rb2, rb3);
            __syncthreads();
            if (kb < 7) {   // issue next k-step's loads; latency hides under MFMA
                const float* pA = srcA + (kb + 1) * 64;
                const float* pB = srcB + (kb + 1) * 64;
                ra0 = *(const float4*)(pA + 0);
                ra1 = *(const float4*)(pA + 4);
                ra2 = *(const float4*)(pA + 8);
                ra3 = *(const float4*)(pA + 12);
                rb0 = *(const float4*)(pB + 0);
                rb1 = *(const float4*)(pB + 4);
                rb2 = *(const float4*)(pB + 8);
                rb3 = *(const float4*)(pB + 12);
            }
            #pragma unroll
            for (int ks = 0; ks < 2; ++ks) {
                const int ca = ((ks * 4 + quad) ^ swz) * 16;
                const short8 a = *(const short8*)(La + rowOffA + ca);
                #pragma unroll
                for (int t = 0; t < 4; ++t) {
                    const short8 b = *(const short8*)(Lb + (t * 16 + ln) * 128 + ca);
                    acc[t] = __builtin_amdgcn_mfma_f32_16x16x32_bf16(a, b, acc[t], 0, 0, 0);
                }
            }
            cur ^= 1;
        }

        // C/D layout: col = lane&15, row = quad*4 + reg.
        const size_t drn = (size_t)2 * BATCH * 4096;
        const size_t din = drn + (size_t)BATCH * DDIM;
        const int woff = ct * 32;
        #pragma unroll
        for (int p = 0; p < 2; ++p) {
            const int colg = woff + p * 16 + ln;     // global D col
            const float br = b_Dr[colg];
            const float bi = b_Di[colg];
            float dr[4], di[4], ps[4];
            #pragma unroll
            for (int i = 0; i < 4; ++i) {
                dr[i] = acc[2 * p][i] + br;
                di[i] = acc[2 * p + 1][i] + bi;
                ps[i] = dr[i] * dr[i] + di[i] * di[i];
            }
            #pragma unroll
            for (int i = 0; i < 4; ++i) {
                ps[i] += __shfl_xor(ps[i], 1);
                ps[i] += __shfl_xor(ps[i], 2);
                ps[i] += __shfl_xor(ps[i], 4);
                ps[i] += __shfl_xor(ps[i], 8);       // sum over 16 cols of c-block
            }
            #pragma unroll
            for (int i = 0; i < 4; ++i) {
                const float scale = 2.0f / sqrtf(8.0f * ps[i]);
                const size_t row_g = (size_t)(row0 + wv * 16 + quad * 4 + i);
                out[drn + row_g * DDIM + colg] = dr[i] * scale;
                out[din + row_g * DDIM + colg] = di[i] * scale;
            }
        }
    } else if (beta < 4608) {
        // ---- A_real / A_imag fill with inline fp32 theta ----
        const int fb = beta - 512;
        const int b  = fb >> 2;                // batch row
        const int rg = fb & 3;                 // 16-antenna slice
        const int tl = tid >> 4;               // 0..15 within slice
        const int j  = tid & 15;               // float4 col chunk / dot lane
        const int t  = rg * 16 + tl;           // antenna row 0..63

        // theta[b][t] = dot(x[b,:], W_A[t,:]) + b_A[t], 16 lanes per row
        const float* xr = x   + (size_t)b * FEAT + j * 4;
        const float* wr = W_A + (size_t)t * FEAT + j * 4;
        float4 a = {0.f, 0.f, 0.f, 0.f};
        #pragma unroll
        for (int it = 0; it < 8; ++it) {
            const float4 xv = *(const float4*)(xr + it * 64);
            const float4 wv = *(const float4*)(wr + it * 64);
            a.x = fmaf(xv.x, wv.x, a.x);
            a.y = fmaf(xv.y, wv.y, a.y);
            a.z = fmaf(xv.z, wv.z, a.z);
            a.w = fmaf(xv.w, wv.w, a.w);
        }
        float th = (a.x + a.y) + (a.z + a.w);
        th += __shfl_xor(th, 1);
        th += __shfl_xor(th, 2);
        th += __shfl_xor(th, 4);
        th += __shfl_xor(th, 8);               // full dot in all 16 lanes
        th += b_A[t];

        float4 vr = {0.f, 0.f, 0.f, 0.f};
        float4 vi = {0.f, 0.f, 0.f, 0.f};
        if ((t >> 2) == j) {                   // diagonal chunk
            float sn, cs;
            sincosf(th, &sn, &cs);
            ((float*)&vr)[t & 3] = cs;
            ((float*)&vi)[t & 3] = sn;
        }
        const size_t off = (size_t)b * 4096 + t * 64 + j * 4;
        *(float4*)(out + off) = vr;
        *(float4*)(out + (size_t)BATCH * 4096 + off) = vi;
    } else {
        // ---- CSet pass-through ----
        const int cb = beta - 4608;            // 0..15
        const size_t base = (size_t)2 * BATCH * 4096 + (size_t)2 * BATCH * DDIM;
        ((float4*)(out + base))[cb * 256 + tid] = ((const float4*)cset)[cb * 256 + tid];
    }
}

extern "C" void kernel_launch(void* const* d_in, const int* in_sizes, int n_in,
                              void* d_out, int out_size, void* d_ws, size_t ws_size,
                              hipStream_t stream) {
    const float* x    = (const float*)d_in[0];
    const float* W_A  = (const float*)d_in[1];
    const float* b_A  = (const float*)d_in[2];
    const float* W_Dr = (const float*)d_in[3];
    const float* b_Dr = (const float*)d_in[4];
    const float* W_Di = (const float*)d_in[5];
    const float* b_Di = (const float*)d_in[6];
    const float* CSet = (const float*)d_in[7];
    float* out = (float*)d_out;

    k_mega<<<4624, 256, 0, stream>>>(x, W_A, b_A, W_Dr, b_Dr, W_Di, b_Di, CSet, out);
}

// Round 5
// 103.421 us; speedup vs baseline: 1.0655x; 1.0655x over previous
//
#include <hip/hip_runtime.h>
#include <math.h>

// Problem constants
#define BATCH 1024
#define FEAT  512
#define NT    64
#define DDIM  1024          // CSETSIZE(64) * Nrf(4) * Nrf(4)

typedef __attribute__((ext_vector_type(8))) short  short8;
typedef __attribute__((ext_vector_type(4))) float  floatx4;

// ws layout (bytes):
//   A-image : 16 row-tiles x 8 k-tiles x 8 KB  = 1,048,576
//   B-image : 32 col-tiles x 8 k-tiles x 8 KB  = 2,097,152  (Dr/Di interleaved)
//   theta   : BATCH*NT fp32                    =   262,144
#define AIMG_OFF  0
#define BIMG_OFF  1048576
#define THETA_OFF 3145728

// fp32 -> bf16 round-to-nearest-even
__device__ __forceinline__ unsigned short bf16rne(float f) {
    unsigned int u = __float_as_uint(f);
    return (unsigned short)((u + 0x7fffu + ((u >> 16) & 1u)) >> 16);
}

__device__ __forceinline__ void gld16(const unsigned char* g, unsigned char* l) {
    __builtin_amdgcn_global_load_lds(
        (const __attribute__((address_space(1))) unsigned int*)g,
        (__attribute__((address_space(3))) unsigned int*)l, 16, 0, 0);
}

// nontemporal 16B store: builtin requires a native clang vector type,
// not HIP_vector_type — go through ext_vector_type floatx4.
__device__ __forceinline__ void nt_store4(float* p, float a, float b, float c, float d) {
    floatx4 v = {a, b, c, d};
    __builtin_nontemporal_store(v, (floatx4*)p);
}

__device__ __forceinline__ void nt_store1(float* p, float v) {
    __builtin_nontemporal_store(v, p);
}

// ===========================================================================
// K0: everything the mega kernel depends on, kept tiny (~2-3 us).
//   blocks [0,256):   bf16 image conversion (A-image: x, B-image: Dr/Di),
//                     256 threads x 3 items each.
//   blocks [256,512): theta = x @ W_A^T + b_A in exact fp32, 16-lane
//                     cooperative dots (runs on VALU while convert blocks
//                     are memory-bound).
// Image tile format (8 KB = 64 rows x 64 k bf16, 16B chunks XOR-swizzled:
// chunk c of row r at position c^(r&7)). B-image col-tile ct interleaves
// Dr/Di per 16-col c-block: row n -> g=n>>5, h=(n>>4)&1, pos=n&15 ->
// (h?W_Di:W_Dr) col ct*32+g*16+pos.
// ===========================================================================
__global__ __launch_bounds__(256) void k0_prep(
    const float* __restrict__ x,
    const float* __restrict__ W_A,
    const float* __restrict__ b_A,
    const float* __restrict__ W_Dr,
    const float* __restrict__ W_Di,
    unsigned char* __restrict__ ws)
{
    const int beta = blockIdx.x;
    const int tid  = threadIdx.x;

    if (beta < 256) {
        // ---- image conversion ----
        unsigned short* aimg = (unsigned short*)(ws + AIMG_OFF);
        unsigned short* bimg = (unsigned short*)(ws + BIMG_OFF);
        const int gtid = beta * 256 + tid;
        #pragma unroll
        for (int v = 0; v < 3; ++v) {
            const int idx = gtid + v * 65536;
            const float* src;
            unsigned short* dst;
            if (idx < 65536) {                 // A-image: x
                const int rt = idx >> 12, kb = (idx >> 9) & 7;
                const int r  = (idx >> 3) & 63, c = idx & 7;
                src = x + ((size_t)(rt * 64 + r) * FEAT + kb * 64 + c * 8);
                dst = aimg + ((rt * 8 + kb) * 4096 + r * 64 + ((c ^ (r & 7)) * 8));
            } else {                           // B-image: W_Dr/W_Di interleaved
                const int j  = idx - 65536;
                const int ct = j >> 12, kb = (j >> 9) & 7;
                const int n  = (j >> 3) & 63, c = j & 7;
                const int g = n >> 5, h = (n >> 4) & 1, pos = n & 15;
                const float* wrow =
                    (h ? W_Di : W_Dr) + (size_t)(ct * 32 + g * 16 + pos) * FEAT;
                src = wrow + kb * 64 + c * 8;
                dst = bimg + ((ct * 8 + kb) * 4096 + n * 64 + ((c ^ (n & 7)) * 8));
            }
            const float4 v0 = *(const float4*)src;
            const float4 v1 = *(const float4*)(src + 4);
            short8 o;
            o[0] = (short)bf16rne(v0.x); o[1] = (short)bf16rne(v0.y);
            o[2] = (short)bf16rne(v0.z); o[3] = (short)bf16rne(v0.w);
            o[4] = (short)bf16rne(v1.x); o[5] = (short)bf16rne(v1.y);
            o[6] = (short)bf16rne(v1.z); o[7] = (short)bf16rne(v1.w);
            *(short8*)dst = o;
        }
    } else {
        // ---- theta = x @ W_A^T + b_A (exact fp32) ----
        float* theta = (float*)(ws + THETA_OFF);
        const int tb = beta - 256;             // 0..255 -> 4 batch rows each
        const int hi = tid >> 4;               // 0..15: dot slot within pass
        const int j  = tid & 15;               // 16-lane split of FEAT
        #pragma unroll 1
        for (int p = 0; p < 16; ++p) {
            const int d = p * 16 + hi;         // 0..255
            const int b = tb * 4 + (d >> 6);
            const int t = d & 63;
            const float* xr = x   + (size_t)b * FEAT + j * 4;
            const float* wr = W_A + (size_t)t * FEAT + j * 4;
            float4 a = {0.f, 0.f, 0.f, 0.f};
            #pragma unroll
            for (int it = 0; it < 8; ++it) {
                const float4 xv = *(const float4*)(xr + it * 64);
                const float4 wv = *(const float4*)(wr + it * 64);
                a.x = fmaf(xv.x, wv.x, a.x);
                a.y = fmaf(xv.y, wv.y, a.y);
                a.z = fmaf(xv.z, wv.z, a.z);
                a.w = fmaf(xv.w, wv.w, a.w);
            }
            float th = (a.x + a.y) + (a.z + a.w);
            th += __shfl_xor(th, 1);
            th += __shfl_xor(th, 2);
            th += __shfl_xor(th, 4);
            th += __shfl_xor(th, 8);
            if (j == 0) theta[tb * 256 + d] = th + b_A[t];
        }
    }
}

// ===========================================================================
// K1 (mega): GEMM + fill + CSet in ONE launch; the D-GEMM (needs only K0's
// 3 MB of images) runs CONCURRENTLY with the 34 MB A_real/A_imag fill.
//   blocks [0,512):     MFMA D-GEMM, 64x64 tiles. rt=bid&15, ct=bid>>4.
//                       Pure global_load_lds staging, double-buffered.
//   blocks [512,4608):  A_real/A_imag diagonal fill — pure streaming now:
//                       1 theta load + sincos + nontemporal float4 stores.
//   blocks [4608,4624): CSet pass-through (nontemporal).
// All output stores nontemporal: write-once data, keep L2 for GEMM images.
// ===========================================================================
__global__ __launch_bounds__(256) void k1_mega(
    const unsigned char* __restrict__ ws,
    const float* __restrict__ b_Dr,
    const float* __restrict__ b_Di,
    const float* __restrict__ cset,
    float* __restrict__ out)
{
    __shared__ __align__(16) unsigned char smem[32768];   // 2 bufs x (8KB A + 8KB B)

    const int beta = blockIdx.x;
    const int tid  = threadIdx.x;

    if (beta < 512) {
        // ---- MFMA D-GEMM ----
        const int rt   = beta & 15;
        const int ct   = beta >> 4;        // 0..31
        const int lane = tid & 63;
        const int wv   = tid >> 6;
        const int ln   = lane & 15;
        const int quad = lane >> 4;
        const int row0 = rt * 64;

        const unsigned char* Atiles = ws + AIMG_OFF + (size_t)rt * 8 * 8192;
        const unsigned char* Btiles = ws + BIMG_OFF + (size_t)ct * 8 * 8192;

        // per-wave DMA chunks: 2x1KB of A + 2x1KB of B per k-step
        const int g0 = (wv * 2 + 0) * 1024;
        const int g1 = (wv * 2 + 1) * 1024;
        const int lo = lane * 16;

        floatx4 acc[4] = {{0,0,0,0},{0,0,0,0},{0,0,0,0},{0,0,0,0}};

        // prefetch kb=0 into buf 0
        {
            unsigned char* La = smem;
            unsigned char* Lb = smem + 8192;
            gld16(Atiles + g0 + lo, La + g0);
            gld16(Atiles + g1 + lo, La + g1);
            gld16(Btiles + g0 + lo, Lb + g0);
            gld16(Btiles + g1 + lo, Lb + g1);
        }

        const int rowOffA = (wv * 16 + ln) * 128;
        const int swz = ln & 7;
        int cur = 0;

        #pragma unroll 1
        for (int kb = 0; kb < 8; ++kb) {
            __syncthreads();   // drains vmcnt(0): buf 'cur' staged; prev frag reads done
            if (kb < 7) {      // prefetch next k-step into the other buffer
                const unsigned char* At = Atiles + (kb + 1) * 8192;
                const unsigned char* Bt = Btiles + (kb + 1) * 8192;
                unsigned char* La = smem + (cur ^ 1) * 16384;
                unsigned char* Lb = La + 8192;
                gld16(At + g0 + lo, La + g0);
                gld16(At + g1 + lo, La + g1);
                gld16(Bt + g0 + lo, Lb + g0);
                gld16(Bt + g1 + lo, Lb + g1);
            }
            const unsigned char* La = smem + cur * 16384;
            const unsigned char* Lb = La + 8192;
            #pragma unroll
            for (int ks = 0; ks < 2; ++ks) {
                const int ca = ((ks * 4 + quad) ^ swz) * 16;
                const short8 a = *(const short8*)(La + rowOffA + ca);
                #pragma unroll
                for (int t = 0; t < 4; ++t) {
                    const short8 b = *(const short8*)(Lb + (t * 16 + ln) * 128 + ca);
                    acc[t] = __builtin_amdgcn_mfma_f32_16x16x32_bf16(a, b, acc[t], 0, 0, 0);
                }
            }
            cur ^= 1;
        }

        // C/D layout: col = lane&15, row = quad*4 + reg.
        const size_t drn = (size_t)2 * BATCH * 4096;
        const size_t din = drn + (size_t)BATCH * DDIM;
        const int woff = ct * 32;
        #pragma unroll
        for (int p = 0; p < 2; ++p) {
            const int colg = woff + p * 16 + ln;     // global D col
            const float br = b_Dr[colg];
            const float bi = b_Di[colg];
            float dr[4], di[4], ps[4];
            #pragma unroll
            for (int i = 0; i < 4; ++i) {
                dr[i] = acc[2 * p][i] + br;
                di[i] = acc[2 * p + 1][i] + bi;
                ps[i] = dr[i] * dr[i] + di[i] * di[i];
            }
            #pragma unroll
            for (int i = 0; i < 4; ++i) {
                ps[i] += __shfl_xor(ps[i], 1);
                ps[i] += __shfl_xor(ps[i], 2);
                ps[i] += __shfl_xor(ps[i], 4);
                ps[i] += __shfl_xor(ps[i], 8);       // sum over 16 cols of c-block
            }
            #pragma unroll
            for (int i = 0; i < 4; ++i) {
                const float scale = 2.0f / sqrtf(8.0f * ps[i]);
                const size_t row_g = (size_t)(row0 + wv * 16 + quad * 4 + i);
                nt_store1(&out[drn + row_g * DDIM + colg], dr[i] * scale);
                nt_store1(&out[din + row_g * DDIM + colg], di[i] * scale);
            }
        }
    } else if (beta < 4608) {
        // ---- A_real / A_imag fill: pure streaming ----
        const float* theta = (const float*)(ws + THETA_OFF);
        const int fb = beta - 512;
        const int b  = fb >> 2;                // batch row
        const int rg = fb & 3;                 // 16-antenna slice
        const int tl = tid >> 4;               // 0..15 within slice
        const int j  = tid & 15;               // float4 col chunk
        const int t  = rg * 16 + tl;           // antenna row 0..63

        const float th = theta[b * NT + t];    // broadcast within 16-lane group

        float r0 = 0.f, r1 = 0.f, r2 = 0.f, r3 = 0.f;
        float i0 = 0.f, i1 = 0.f, i2 = 0.f, i3 = 0.f;
        if ((t >> 2) == j) {                   // diagonal chunk
            float sn, cs;
            sincosf(th, &sn, &cs);
            const int k = t & 3;
            if (k == 0) { r0 = cs; i0 = sn; }
            else if (k == 1) { r1 = cs; i1 = sn; }
            else if (k == 2) { r2 = cs; i2 = sn; }
            else { r3 = cs; i3 = sn; }
        }
        const size_t off = (size_t)b * 4096 + t * 64 + j * 4;
        nt_store4(out + off, r0, r1, r2, r3);
        nt_store4(out + (size_t)BATCH * 4096 + off, i0, i1, i2, i3);
    } else {
        // ---- CSet pass-through ----
        const int cb = beta - 4608;            // 0..15
        const size_t base = (size_t)2 * BATCH * 4096 + (size_t)2 * BATCH * DDIM;
        const floatx4 v = ((const floatx4*)cset)[cb * 256 + tid];
        __builtin_nontemporal_store(v, &((floatx4*)(out + base))[cb * 256 + tid]);
    }
}

extern "C" void kernel_launch(void* const* d_in, const int* in_sizes, int n_in,
                              void* d_out, int out_size, void* d_ws, size_t ws_size,
                              hipStream_t stream) {
    const float* x    = (const float*)d_in[0];
    const float* W_A  = (const float*)d_in[1];
    const float* b_A  = (const float*)d_in[2];
    const float* W_Dr = (const float*)d_in[3];
    const float* b_Dr = (const float*)d_in[4];
    const float* W_Di = (const float*)d_in[5];
    const float* b_Di = (const float*)d_in[6];
    const float* CSet = (const float*)d_in[7];
    float* out = (float*)d_out;
    unsigned char* ws = (unsigned char*)d_ws;

    k0_prep<<<512, 256, 0, stream>>>(x, W_A, b_A, W_Dr, W_Di, ws);
    k1_mega<<<4624, 256, 0, stream>>>(ws, b_Dr, b_Di, CSet, out);
}

// Round 7
// 102.968 us; speedup vs baseline: 1.0702x; 1.0044x over previous
//
#include <hip/hip_runtime.h>
#include <math.h>

// Problem constants
#define BATCH 1024
#define FEAT  512
#define NT    64
#define DDIM  1024          // CSETSIZE(64) * Nrf(4) * Nrf(4)

typedef __attribute__((ext_vector_type(8))) short  short8;
typedef __attribute__((ext_vector_type(4))) float  floatx4;

// ws layout (bytes):
//   A-image : 16 row-tiles x 8 k-tiles x 8 KB  = 1,048,576
//   B-image : 32 col-tiles x 8 k-tiles x 8 KB  = 2,097,152  (Dr/Di interleaved)
//   theta   : BATCH*NT fp32                    =   262,144
#define AIMG_OFF  0
#define BIMG_OFF  1048576
#define THETA_OFF 3145728

// fp32 -> bf16 round-to-nearest-even
__device__ __forceinline__ unsigned short bf16rne(float f) {
    unsigned int u = __float_as_uint(f);
    return (unsigned short)((u + 0x7fffu + ((u >> 16) & 1u)) >> 16);
}

__device__ __forceinline__ void gld16(const unsigned char* g, unsigned char* l) {
    __builtin_amdgcn_global_load_lds(
        (const __attribute__((address_space(1))) unsigned int*)g,
        (__attribute__((address_space(3))) unsigned int*)l, 16, 0, 0);
}

// nontemporal stores: builtin requires native clang vector types.
__device__ __forceinline__ void nt_store4(float* p, float a, float b, float c, float d) {
    floatx4 v = {a, b, c, d};
    __builtin_nontemporal_store(v, (floatx4*)p);
}

__device__ __forceinline__ void nt_store1(float* p, float v) {
    __builtin_nontemporal_store(v, p);
}

// ===========================================================================
// K0: everything the mega kernel depends on, kept tiny (~2-3 us).
//   blocks [0,256):   bf16 image conversion (A-image: x, B-image: Dr/Di),
//                     256 threads x 3 items each.
//   blocks [256,512): theta = x @ W_A^T + b_A in exact fp32, 16-lane
//                     cooperative dots (VALU work, overlaps convert's
//                     memory-bound blocks).
// Image tile format (8 KB = 64 rows x 64 k bf16, 16B chunks XOR-swizzled:
// chunk c of row r at position c^(r&7)). B-image col-tile ct interleaves
// Dr/Di per 16-col c-block: row n -> g=n>>5, h=(n>>4)&1, pos=n&15 ->
// (h?W_Di:W_Dr) col ct*32+g*16+pos.
// ===========================================================================
__global__ __launch_bounds__(256) void k0_prep(
    const float* __restrict__ x,
    const float* __restrict__ W_A,
    const float* __restrict__ b_A,
    const float* __restrict__ W_Dr,
    const float* __restrict__ W_Di,
    unsigned char* __restrict__ ws)
{
    const int beta = blockIdx.x;
    const int tid  = threadIdx.x;

    if (beta < 256) {
        // ---- image conversion ----
        unsigned short* aimg = (unsigned short*)(ws + AIMG_OFF);
        unsigned short* bimg = (unsigned short*)(ws + BIMG_OFF);
        const int gtid = beta * 256 + tid;
        #pragma unroll
        for (int v = 0; v < 3; ++v) {
            const int idx = gtid + v * 65536;
            const float* src;
            unsigned short* dst;
            if (idx < 65536) {                 // A-image: x
                const int rt = idx >> 12, kb = (idx >> 9) & 7;
                const int r  = (idx >> 3) & 63, c = idx & 7;
                src = x + ((size_t)(rt * 64 + r) * FEAT + kb * 64 + c * 8);
                dst = aimg + ((rt * 8 + kb) * 4096 + r * 64 + ((c ^ (r & 7)) * 8));
            } else {                           // B-image: W_Dr/W_Di interleaved
                const int j  = idx - 65536;
                const int ct = j >> 12, kb = (j >> 9) & 7;
                const int n  = (j >> 3) & 63, c = j & 7;
                const int g = n >> 5, h = (n >> 4) & 1, pos = n & 15;
                const float* wrow =
                    (h ? W_Di : W_Dr) + (size_t)(ct * 32 + g * 16 + pos) * FEAT;
                src = wrow + kb * 64 + c * 8;
                dst = bimg + ((ct * 8 + kb) * 4096 + n * 64 + ((c ^ (n & 7)) * 8));
            }
            const float4 v0 = *(const float4*)src;
            const float4 v1 = *(const float4*)(src + 4);
            short8 o;
            o[0] = (short)bf16rne(v0.x); o[1] = (short)bf16rne(v0.y);
            o[2] = (short)bf16rne(v0.z); o[3] = (short)bf16rne(v0.w);
            o[4] = (short)bf16rne(v1.x); o[5] = (short)bf16rne(v1.y);
            o[6] = (short)bf16rne(v1.z); o[7] = (short)bf16rne(v1.w);
            *(short8*)dst = o;
        }
    } else {
        // ---- theta = x @ W_A^T + b_A (exact fp32) ----
        float* theta = (float*)(ws + THETA_OFF);
        const int tb = beta - 256;             // 0..255 -> 4 batch rows each
        const int hi = tid >> 4;               // 0..15: dot slot within pass
        const int j  = tid & 15;               // 16-lane split of FEAT
        #pragma unroll 1
        for (int p = 0; p < 16; ++p) {
            const int d = p * 16 + hi;         // 0..255
            const int b = tb * 4 + (d >> 6);
            const int t = d & 63;
            const float* xr = x   + (size_t)b * FEAT + j * 4;
            const float* wr = W_A + (size_t)t * FEAT + j * 4;
            float4 a = {0.f, 0.f, 0.f, 0.f};
            #pragma unroll
            for (int it = 0; it < 8; ++it) {
                const float4 xv = *(const float4*)(xr + it * 64);
                const float4 wv = *(const float4*)(wr + it * 64);
                a.x = fmaf(xv.x, wv.x, a.x);
                a.y = fmaf(xv.y, wv.y, a.y);
                a.z = fmaf(xv.z, wv.z, a.z);
                a.w = fmaf(xv.w, wv.w, a.w);
            }
            float th = (a.x + a.y) + (a.z + a.w);
            th += __shfl_xor(th, 1);
            th += __shfl_xor(th, 2);
            th += __shfl_xor(th, 4);
            th += __shfl_xor(th, 8);
            if (j == 0) theta[tb * 256 + d] = th + b_A[t];
        }
    }
}

// ===========================================================================
// K1 (mega): GEMM + fill + CSet in ONE launch; the D-GEMM (needs only K0's
// 3 MB of images) runs CONCURRENTLY with the 34 MB A_real/A_imag fill.
//   blocks [0,512):     MFMA D-GEMM, 64x64 tiles. rt=bid&15, ct=bid>>4.
//                       Pure global_load_lds staging, double-buffered.
//   blocks [512,1536):  A_real/A_imag fill, ONE BATCH ROW PER BLOCK
//                       (coarsened 4x: 8 nontemporal 16B stores/thread).
//                       Total grid 1552 ~= 6 blocks/CU -> single dispatch
//                       round, no ramp/tail.
//   blocks [1536,1552): CSet pass-through (nontemporal).
// All output stores nontemporal: write-once data, keep L2 for GEMM images.
// ===========================================================================
__global__ __launch_bounds__(256) void k1_mega(
    const unsigned char* __restrict__ ws,
    const float* __restrict__ b_Dr,
    const float* __restrict__ b_Di,
    const float* __restrict__ cset,
    float* __restrict__ out)
{
    __shared__ __align__(16) unsigned char smem[32768];   // 2 bufs x (8KB A + 8KB B)

    const int beta = blockIdx.x;
    const int tid  = threadIdx.x;

    if (beta < 512) {
        // ---- MFMA D-GEMM ----
        const int rt   = beta & 15;
        const int ct   = beta >> 4;        // 0..31
        const int lane = tid & 63;
        const int wv   = tid >> 6;
        const int ln   = lane & 15;
        const int quad = lane >> 4;
        const int row0 = rt * 64;

        const unsigned char* Atiles = ws + AIMG_OFF + (size_t)rt * 8 * 8192;
        const unsigned char* Btiles = ws + BIMG_OFF + (size_t)ct * 8 * 8192;

        // per-wave DMA chunks: 2x1KB of A + 2x1KB of B per k-step
        const int g0 = (wv * 2 + 0) * 1024;
        const int g1 = (wv * 2 + 1) * 1024;
        const int lo = lane * 16;

        floatx4 acc[4] = {{0,0,0,0},{0,0,0,0},{0,0,0,0},{0,0,0,0}};

        // prefetch kb=0 into buf 0
        {
            unsigned char* La = smem;
            unsigned char* Lb = smem + 8192;
            gld16(Atiles + g0 + lo, La + g0);
            gld16(Atiles + g1 + lo, La + g1);
            gld16(Btiles + g0 + lo, Lb + g0);
            gld16(Btiles + g1 + lo, Lb + g1);
        }

        const int rowOffA = (wv * 16 + ln) * 128;
        const int swz = ln & 7;
        int cur = 0;

        #pragma unroll 1
        for (int kb = 0; kb < 8; ++kb) {
            __syncthreads();   // drains vmcnt(0): buf 'cur' staged; prev frag reads done
            if (kb < 7) {      // prefetch next k-step into the other buffer
                const unsigned char* At = Atiles + (kb + 1) * 8192;
                const unsigned char* Bt = Btiles + (kb + 1) * 8192;
                unsigned char* La = smem + (cur ^ 1) * 16384;
                unsigned char* Lb = La + 8192;
                gld16(At + g0 + lo, La + g0);
                gld16(At + g1 + lo, La + g1);
                gld16(Bt + g0 + lo, Lb + g0);
                gld16(Bt + g1 + lo, Lb + g1);
            }
            const unsigned char* La = smem + cur * 16384;
            const unsigned char* Lb = La + 8192;
            #pragma unroll
            for (int ks = 0; ks < 2; ++ks) {
                const int ca = ((ks * 4 + quad) ^ swz) * 16;
                const short8 a = *(const short8*)(La + rowOffA + ca);
                #pragma unroll
                for (int t = 0; t < 4; ++t) {
                    const short8 b = *(const short8*)(Lb + (t * 16 + ln) * 128 + ca);
                    acc[t] = __builtin_amdgcn_mfma_f32_16x16x32_bf16(a, b, acc[t], 0, 0, 0);
                }
            }
            cur ^= 1;
        }

        // C/D layout: col = lane&15, row = quad*4 + reg.
        const size_t drn = (size_t)2 * BATCH * 4096;
        const size_t din = drn + (size_t)BATCH * DDIM;
        const int woff = ct * 32;
        #pragma unroll
        for (int p = 0; p < 2; ++p) {
            const int colg = woff + p * 16 + ln;     // global D col
            const float br = b_Dr[colg];
            const float bi = b_Di[colg];
            float dr[4], di[4], ps[4];
            #pragma unroll
            for (int i = 0; i < 4; ++i) {
                dr[i] = acc[2 * p][i] + br;
                di[i] = acc[2 * p + 1][i] + bi;
                ps[i] = dr[i] * dr[i] + di[i] * di[i];
            }
            #pragma unroll
            for (int i = 0; i < 4; ++i) {
                ps[i] += __shfl_xor(ps[i], 1);
                ps[i] += __shfl_xor(ps[i], 2);
                ps[i] += __shfl_xor(ps[i], 4);
                ps[i] += __shfl_xor(ps[i], 8);       // sum over 16 cols of c-block
            }
            #pragma unroll
            for (int i = 0; i < 4; ++i) {
                const float scale = 2.0f / sqrtf(8.0f * ps[i]);
                const size_t row_g = (size_t)(row0 + wv * 16 + quad * 4 + i);
                nt_store1(&out[drn + row_g * DDIM + colg], dr[i] * scale);
                nt_store1(&out[din + row_g * DDIM + colg], di[i] * scale);
            }
        }
    } else if (beta < 1536) {
        // ---- A_real / A_imag fill: one batch row per block, pure streaming ----
        const float* theta = (const float*)(ws + THETA_OFF);
        const int b  = beta - 512;             // batch row 0..1023
        const int tl = tid >> 4;               // 0..15 within each 16-antenna slice
        const int j  = tid & 15;               // float4 col chunk

        // hoist all 4 theta loads (L2-resident broadcast within 16-lane groups)
        float th[4];
        #pragma unroll
        for (int rg = 0; rg < 4; ++rg) th[rg] = theta[b * NT + rg * 16 + tl];

        #pragma unroll
        for (int rg = 0; rg < 4; ++rg) {
            const int t = rg * 16 + tl;        // antenna row 0..63
            float r0 = 0.f, r1 = 0.f, r2 = 0.f, r3 = 0.f;
            float i0 = 0.f, i1 = 0.f, i2 = 0.f, i3 = 0.f;
            if ((t >> 2) == j) {               // diagonal chunk (<=1 per thread)
                float sn, cs;
                sincosf(th[rg], &sn, &cs);
                const int k = t & 3;
                if (k == 0) { r0 = cs; i0 = sn; }
                else if (k == 1) { r1 = cs; i1 = sn; }
                else if (k == 2) { r2 = cs; i2 = sn; }
                else { r3 = cs; i3 = sn; }
            }
            const size_t off = (size_t)b * 4096 + t * 64 + j * 4;
            nt_store4(out + off, r0, r1, r2, r3);
            nt_store4(out + (size_t)BATCH * 4096 + off, i0, i1, i2, i3);
        }
    } else {
        // ---- CSet pass-through ----
        const int cb = beta - 1536;            // 0..15
        const size_t base = (size_t)2 * BATCH * 4096 + (size_t)2 * BATCH * DDIM;
        const floatx4 v = ((const floatx4*)cset)[cb * 256 + tid];
        __builtin_nontemporal_store(v, &((floatx4*)(out + base))[cb * 256 + tid]);
    }
}

extern "C" void kernel_launch(void* const* d_in, const int* in_sizes, int n_in,
                              void* d_out, int out_size, void* d_ws, size_t ws_size,
                              hipStream_t stream) {
    const float* x    = (const float*)d_in[0];
    const float* W_A  = (const float*)d_in[1];
    const float* b_A  = (const float*)d_in[2];
    const float* W_Dr = (const float*)d_in[3];
    const float* b_Dr = (const float*)d_in[4];
    const float* W_Di = (const float*)d_in[5];
    const float* b_Di = (const float*)d_in[6];
    const float* CSet = (const float*)d_in[7];
    float* out = (float*)d_out;
    unsigned char* ws = (unsigned char*)d_ws;

    k0_prep<<<512, 256, 0, stream>>>(x, W_A, b_A, W_Dr, W_Di, ws);
    k1_mega<<<1552, 256, 0, stream>>>(ws, b_Dr, b_Di, CSet, out);
}